// Round 2
// baseline (647.086 us; speedup 1.0000x reference)
//
#include <hip/hip_runtime.h>
#include <stdint.h>

#define N_TOK 65536
#define CDIM  512
#define C3    1536
#define HEADS 8
#define DHEAD 64
#define KTOK  256
#define PGRP  256

typedef __attribute__((ext_vector_type(8))) short bf16x8;
typedef __attribute__((ext_vector_type(4))) float f32x4;

__device__ __forceinline__ unsigned short f2bf(float f) {
  union { float f; unsigned u; } t; t.f = f;
  return (unsigned short)((t.u + 0x7fffu + ((t.u >> 16) & 1u)) >> 16);
}

// ------------- elementwise f32 -> bf16 (vectorized) ------------------------
__global__ __launch_bounds__(256) void cvt_f32_bf16(const float* __restrict__ in,
                                                    unsigned short* __restrict__ out) {
  size_t i = ((size_t)blockIdx.x * 256 + threadIdx.x) * 4;
  float4 v = *(const float4*)(in + i);
  ushort4 o;
  o.x = f2bf(v.x); o.y = f2bf(v.y); o.z = f2bf(v.z); o.w = f2bf(v.w);
  *(ushort4*)(out + i) = o;
}

// ------------- transpose + convert (f32 R x Cc -> bf16 Cc x R) -------------
__global__ __launch_bounds__(256) void transpose_cvt(const float* __restrict__ in,
                                                     unsigned short* __restrict__ out,
                                                     int R, int Cc) {
  __shared__ float tile[32][33];
  int c0 = blockIdx.x * 32, r0 = blockIdx.y * 32;
  int tx = threadIdx.x & 31, ty = threadIdx.x >> 5;  // 32 x 8
  for (int i = ty; i < 32; i += 8)
    tile[i][tx] = in[(size_t)(r0 + i) * Cc + c0 + tx];
  __syncthreads();
  for (int i = ty; i < 32; i += 8)
    out[(size_t)(c0 + i) * R + r0 + tx] = f2bf(tile[tx][i]);
}

// ---------------- GEMM: C[m,n] = A[gather(m),:] @ Bt[n,:]^T + bias[n] ------
// A, Bt bf16; bias f32; output bf16 (OF32=0) or f32 (OF32=1).
// 128x128 tile, BK=64, 256 threads (4 waves 2x2), 16x16x32 bf16 MFMA,
// global_load_lds 16B/lane, 16B-group XOR swizzle on LDS.
template <int OF32>
__global__ __launch_bounds__(256) void gemm_bt(const unsigned short* __restrict__ A,
                                               const unsigned short* __restrict__ Bt,
                                               const float* __restrict__ bias,
                                               void* __restrict__ Cout,
                                               const int* __restrict__ gather,
                                               int Nn, int Kk, int nbn) {
  __shared__ __align__(16) unsigned short As[128 * 64];
  __shared__ __align__(16) unsigned short Bs[128 * 64];
  int bm = blockIdx.x / nbn, bn = blockIdx.x % nbn;
  int m0 = bm * 128, n0 = bn * 128;
  int tid = threadIdx.x;
  int wv = tid >> 6, ln = tid & 63, g = ln >> 4, c = ln & 15;
  int wr = wv >> 1, wc = wv & 1;

  const unsigned short* aptr[4];
  const unsigned short* bptr[4];
#pragma unroll
  for (int i = 0; i < 4; ++i) {
    int s = wv * 256 + i * 64 + ln;   // slot 0..1023, 16B each
    int r = s >> 3, pp = s & 7;
    int cg = pp ^ (r & 7);            // which 8-col group this slot holds
    int ga = gather ? gather[m0 + r] : (m0 + r);
    aptr[i] = A + (size_t)ga * Kk + cg * 8;
    bptr[i] = Bt + (size_t)(n0 + r) * Kk + cg * 8;
  }

  f32x4 acc[4][4];
#pragma unroll
  for (int mi = 0; mi < 4; ++mi)
#pragma unroll
    for (int ni = 0; ni < 4; ++ni)
      acc[mi][ni] = (f32x4){0.f, 0.f, 0.f, 0.f};

  for (int k0 = 0; k0 < Kk; k0 += 64) {
    __syncthreads();
#pragma unroll
    for (int i = 0; i < 4; ++i) {
      __builtin_amdgcn_global_load_lds(
          (__attribute__((address_space(1))) void*)(void*)(aptr[i] + k0),
          (__attribute__((address_space(3))) void*)&As[(wv * 256 + i * 64) * 8],
          16, 0, 0);
      __builtin_amdgcn_global_load_lds(
          (__attribute__((address_space(1))) void*)(void*)(bptr[i] + k0),
          (__attribute__((address_space(3))) void*)&Bs[(wv * 256 + i * 64) * 8],
          16, 0, 0);
    }
    __syncthreads();
#pragma unroll
    for (int kc = 0; kc < 2; ++kc) {
      bf16x8 af[4], bfv[4];
#pragma unroll
      for (int mi = 0; mi < 4; ++mi) {
        int m = wr * 64 + mi * 16 + c;
        af[mi] = *(const bf16x8*)&As[(m * 8 + ((kc * 4 + g) ^ (m & 7))) * 8];
      }
#pragma unroll
      for (int ni = 0; ni < 4; ++ni) {
        int n = wc * 64 + ni * 16 + c;
        bfv[ni] = *(const bf16x8*)&Bs[(n * 8 + ((kc * 4 + g) ^ (n & 7))) * 8];
      }
#pragma unroll
      for (int mi = 0; mi < 4; ++mi)
#pragma unroll
        for (int ni = 0; ni < 4; ++ni)
          acc[mi][ni] = __builtin_amdgcn_mfma_f32_16x16x32_bf16(af[mi], bfv[ni], acc[mi][ni], 0, 0, 0);
    }
  }

#pragma unroll
  for (int ni = 0; ni < 4; ++ni) {
    int col = n0 + wc * 64 + ni * 16 + c;
    float bv = bias[col];
#pragma unroll
    for (int mi = 0; mi < 4; ++mi)
#pragma unroll
      for (int rr = 0; rr < 4; ++rr) {
        int row = m0 + wr * 64 + mi * 16 + g * 4 + rr;
        float v = acc[mi][ni][rr] + bv;
        if (OF32)
          ((float*)Cout)[(size_t)row * Nn + col] = v;
        else
          ((unsigned short*)Cout)[(size_t)row * Nn + col] = f2bf(v);
      }
  }
}

// ---------------- attention: one workgroup per (p, h) ----------------------
// qkv (bf16) is the permuted (N, 1536) buffer; q at col h*64, k at 512+h*64,
// v at 1024+h*64. Output scattered to row order[n] (bf16) so the proj GEMM
// reads contiguously.
__global__ __launch_bounds__(256) void attn_k(const unsigned short* __restrict__ qkv,
                                              const int* __restrict__ order,
                                              unsigned short* __restrict__ attnout) {
  __shared__ __align__(16) unsigned short Ks[KTOK * 64];     // [m][d], XOR-swizzled 16B groups
  __shared__ __align__(16) unsigned short Vt[64 * 256];      // [d][m] transposed, XOR-swizzled
  __shared__ __align__(16) unsigned short Pt[4][16 * 256];   // per-wave P tile, XOR-swizzled

  int p = blockIdx.x >> 3, h = blockIdx.x & 7;
  int tid = threadIdx.x;
  int wv = tid >> 6, ln = tid & 63, g = ln >> 4, c = ln & 15;

  const unsigned short* base = qkv + (size_t)p * KTOK * C3 + h * DHEAD;

  // stage K rows and V transposed
  {
    const unsigned short* krow = base + CDIM + (size_t)tid * C3;
#pragma unroll
    for (int j = 0; j < 8; ++j) {
      bf16x8 kv = *(const bf16x8*)(krow + j * 8);
      *(bf16x8*)&Ks[(tid * 8 + (j ^ (tid & 7))) * 8] = kv;
    }
    const unsigned short* vrow = base + 2 * CDIM + (size_t)tid * C3;
#pragma unroll
    for (int j = 0; j < 8; ++j) {
      bf16x8 vvv = *(const bf16x8*)(vrow + j * 8);
#pragma unroll
      for (int e = 0; e < 8; ++e) {
        int d = j * 8 + e;
        Vt[d * 256 + (((tid >> 3) ^ (d & 7)) << 3) + (tid & 7)] = (unsigned short)vvv[e];
      }
    }
  }
  __syncthreads();

#pragma unroll 1
  for (int t = 0; t < 4; ++t) {
    int q0 = wv * 64 + t * 16;
    const unsigned short* qrow = base + (size_t)(q0 + c) * C3;
    bf16x8 aq0 = *(const bf16x8*)(qrow + g * 8);
    bf16x8 aq1 = *(const bf16x8*)(qrow + 32 + g * 8);

    // S = Q K^T  (16 q-rows x 256 m-cols), C/D: row=g*4+reg (q), col=c
    f32x4 s[16];
#pragma unroll
    for (int mt = 0; mt < 16; ++mt) {
      int m = mt * 16 + c;
      bf16x8 bk0 = *(const bf16x8*)&Ks[(m * 8 + ((0 + g) ^ (m & 7))) * 8];
      bf16x8 bk1 = *(const bf16x8*)&Ks[(m * 8 + ((4 + g) ^ (m & 7))) * 8];
      f32x4 z = (f32x4){0.f, 0.f, 0.f, 0.f};
      z = __builtin_amdgcn_mfma_f32_16x16x32_bf16(aq0, bk0, z, 0, 0, 0);
      s[mt] = __builtin_amdgcn_mfma_f32_16x16x32_bf16(aq1, bk1, z, 0, 0, 0);
    }

    // softmax over m: 16 mt tiles in-reg + 16 lanes (shfl_xor 1..8, same g)
    float mx[4], sm[4];
#pragma unroll
    for (int rr = 0; rr < 4; ++rr) {
      float m1 = s[0][rr];
#pragma unroll
      for (int mt = 1; mt < 16; ++mt) m1 = fmaxf(m1, s[mt][rr]);
#pragma unroll
      for (int off = 1; off < 16; off <<= 1) m1 = fmaxf(m1, __shfl_xor(m1, off, 64));
      mx[rr] = m1;
    }
#pragma unroll
    for (int rr = 0; rr < 4; ++rr) sm[rr] = 0.f;
#pragma unroll
    for (int mt = 0; mt < 16; ++mt)
#pragma unroll
      for (int rr = 0; rr < 4; ++rr) {
        float e = __expf((s[mt][rr] - mx[rr]) * 0.125f);
        s[mt][rr] = e;
        sm[rr] += e;
      }
#pragma unroll
    for (int rr = 0; rr < 4; ++rr) {
      float t2 = sm[rr];
#pragma unroll
      for (int off = 1; off < 16; off <<= 1) t2 += __shfl_xor(t2, off, 64);
      sm[rr] = 1.f / t2;
    }

    // P (normalized, bf16) -> LDS in A-operand-readable layout
    __syncthreads();  // WAR: previous iteration's Pt reads complete everywhere
#pragma unroll
    for (int mt = 0; mt < 16; ++mt)
#pragma unroll
      for (int rr = 0; rr < 4; ++rr) {
        int q = g * 4 + rr;
        int mcol = mt * 16 + c;
        Pt[wv][q * 256 + ((((mcol >> 3) ^ (q & 7))) << 3) + (mcol & 7)] =
            f2bf(s[mt][rr] * sm[rr]);
      }
    __syncthreads();  // RAW: Pt visible before A-operand reads

    // O = P V   (16 q-rows x 64 d-cols)
    f32x4 o[4];
#pragma unroll
    for (int dt = 0; dt < 4; ++dt) o[dt] = (f32x4){0.f, 0.f, 0.f, 0.f};
#pragma unroll
    for (int mc = 0; mc < 8; ++mc) {
      int cgm = mc * 4 + g;
      bf16x8 ap = *(const bf16x8*)&Pt[wv][(c * 32 + (cgm ^ (c & 7))) * 8];
#pragma unroll
      for (int dt = 0; dt < 4; ++dt) {
        int d = dt * 16 + c;
        bf16x8 bv = *(const bf16x8*)&Vt[(d * 32 + (cgm ^ (d & 7))) * 8];
        o[dt] = __builtin_amdgcn_mfma_f32_16x16x32_bf16(ap, bv, o[dt], 0, 0, 0);
      }
    }

    // scatter-store: row order[p*256 + q], col h*64 + d
#pragma unroll
    for (int rr = 0; rr < 4; ++rr) {
      int orow = order[p * KTOK + q0 + g * 4 + rr];
      size_t rb = (size_t)orow * CDIM + h * DHEAD;
#pragma unroll
      for (int dt = 0; dt < 4; ++dt)
        attnout[rb + dt * 16 + c] = f2bf(o[dt][rr]);
    }
  }
}

extern "C" void kernel_launch(void* const* d_in, const int* in_sizes, int n_in,
                              void* d_out, int out_size, void* d_ws, size_t ws_size,
                              hipStream_t stream) {
  const float* feat  = (const float*)d_in[0];
  const int*   order = (const int*)d_in[1];
  // d_in[2] = inverse (unused: we scatter by order instead)
  const float* Wqkv  = (const float*)d_in[3];
  const float* bqkv  = (const float*)d_in[4];
  const float* Wproj = (const float*)d_in[5];
  const float* bproj = (const float*)d_in[6];
  float* out = (float*)d_out;

  // ws layout (bf16 intermediates):
  //   qkv    : N*1536            = 201.3 MB
  //   featb  : N*512             =  67.1 MB  (dead after gemm1; aliased by attn)
  //   wqkvT  : 1536*512          =   1.6 MB
  //   wprojT : 512*512           =   0.5 MB
  char* ws = (char*)d_ws;
  unsigned short* qkv    = (unsigned short*)ws;
  unsigned short* featb  = (unsigned short*)(ws + (size_t)N_TOK * C3 * 2);
  unsigned short* attn   = featb;  // disjoint lifetime
  unsigned short* wqkvT  = (unsigned short*)(ws + (size_t)N_TOK * C3 * 2 + (size_t)N_TOK * CDIM * 2);
  unsigned short* wprojT = wqkvT + C3 * CDIM;

  // f32 -> bf16 conversions
  cvt_f32_bf16<<<(N_TOK * CDIM) / (256 * 4), 256, 0, stream>>>(feat, featb);
  transpose_cvt<<<dim3(C3 / 32, CDIM / 32), 256, 0, stream>>>(Wqkv, wqkvT, CDIM, C3);
  transpose_cvt<<<dim3(CDIM / 32, CDIM / 32), 256, 0, stream>>>(Wproj, wprojT, CDIM, CDIM);

  // qkv[n,:] = feat[order[n],:] @ Wqkv + bqkv   (permuted rows directly)
  gemm_bt<0><<<(N_TOK / 128) * (C3 / 128), 256, 0, stream>>>(
      featb, wqkvT, bqkv, qkv, order, C3, CDIM, C3 / 128);

  // block-local attention, scatter back to original row order
  attn_k<<<PGRP * HEADS, 256, 0, stream>>>(qkv, order, attn);

  // out = attn @ Wproj + bproj  (f32 output)
  gemm_bt<1><<<(N_TOK / 128) * (CDIM / 128), 256, 0, stream>>>(
      attn, wprojT, bproj, out, nullptr, CDIM, CDIM, CDIM / 128);
}

// Round 3
// 644.697 us; speedup vs baseline: 1.0037x; 1.0037x over previous
//
#include <hip/hip_runtime.h>
#include <stdint.h>

#define N_TOK 65536
#define CDIM  512
#define C3    1536
#define HEADS 8
#define DHEAD 64
#define KTOK  256
#define PGRP  256

typedef __attribute__((ext_vector_type(8))) short bf16x8;
typedef __attribute__((ext_vector_type(4))) float f32x4;

__device__ __forceinline__ unsigned short f2bf(float f) {
  union { float f; unsigned u; } t; t.f = f;
  return (unsigned short)((t.u + 0x7fffu + ((t.u >> 16) & 1u)) >> 16);
}

// ------------- elementwise f32 -> bf16 (vectorized) ------------------------
__global__ __launch_bounds__(256) void cvt_f32_bf16(const float* __restrict__ in,
                                                    unsigned short* __restrict__ out) {
  size_t i = ((size_t)blockIdx.x * 256 + threadIdx.x) * 4;
  float4 v = *(const float4*)(in + i);
  ushort4 o;
  o.x = f2bf(v.x); o.y = f2bf(v.y); o.z = f2bf(v.z); o.w = f2bf(v.w);
  *(ushort4*)(out + i) = o;
}

// ------------- transpose + convert (f32 R x Cc -> bf16 Cc x R) -------------
__global__ __launch_bounds__(256) void transpose_cvt(const float* __restrict__ in,
                                                     unsigned short* __restrict__ out,
                                                     int R, int Cc) {
  __shared__ float tile[32][33];
  int c0 = blockIdx.x * 32, r0 = blockIdx.y * 32;
  int tx = threadIdx.x & 31, ty = threadIdx.x >> 5;  // 32 x 8
  for (int i = ty; i < 32; i += 8)
    tile[i][tx] = in[(size_t)(r0 + i) * Cc + c0 + tx];
  __syncthreads();
  for (int i = ty; i < 32; i += 8)
    out[(size_t)(c0 + i) * R + r0 + tx] = f2bf(tile[tx][i]);
}

// ---------------- GEMM: C[m,n] = A[gather(m),:] @ Bt[n,:]^T + bias[n] ------
// A, Bt bf16; bias f32; output bf16 (OF32=0) or f32 (OF32=1).
// 128x128 tile, BK=64, 256 threads (4 waves 2x2), 16x16x32 bf16 MFMA,
// global_load_lds 16B/lane, 16B-group XOR swizzle on LDS.
template <int OF32>
__global__ __launch_bounds__(256) void gemm_bt(const unsigned short* __restrict__ A,
                                               const unsigned short* __restrict__ Bt,
                                               const float* __restrict__ bias,
                                               void* __restrict__ Cout,
                                               const int* __restrict__ gather,
                                               int Nn, int Kk, int nbn) {
  __shared__ __align__(16) unsigned short As[128 * 64];
  __shared__ __align__(16) unsigned short Bs[128 * 64];
  int bm = blockIdx.x / nbn, bn = blockIdx.x % nbn;
  int m0 = bm * 128, n0 = bn * 128;
  int tid = threadIdx.x;
  int wv = tid >> 6, ln = tid & 63, g = ln >> 4, c = ln & 15;
  int wr = wv >> 1, wc = wv & 1;

  const unsigned short* aptr[4];
  const unsigned short* bptr[4];
#pragma unroll
  for (int i = 0; i < 4; ++i) {
    int s = wv * 256 + i * 64 + ln;   // slot 0..1023, 16B each
    int r = s >> 3, pp = s & 7;
    int cg = pp ^ (r & 7);            // which 8-col group this slot holds
    int ga = gather ? gather[m0 + r] : (m0 + r);
    aptr[i] = A + (size_t)ga * Kk + cg * 8;
    bptr[i] = Bt + (size_t)(n0 + r) * Kk + cg * 8;
  }

  f32x4 acc[4][4];
#pragma unroll
  for (int mi = 0; mi < 4; ++mi)
#pragma unroll
    for (int ni = 0; ni < 4; ++ni)
      acc[mi][ni] = (f32x4){0.f, 0.f, 0.f, 0.f};

  for (int k0 = 0; k0 < Kk; k0 += 64) {
    __syncthreads();
#pragma unroll
    for (int i = 0; i < 4; ++i) {
      __builtin_amdgcn_global_load_lds(
          (__attribute__((address_space(1))) void*)(void*)(aptr[i] + k0),
          (__attribute__((address_space(3))) void*)&As[(wv * 256 + i * 64) * 8],
          16, 0, 0);
      __builtin_amdgcn_global_load_lds(
          (__attribute__((address_space(1))) void*)(void*)(bptr[i] + k0),
          (__attribute__((address_space(3))) void*)&Bs[(wv * 256 + i * 64) * 8],
          16, 0, 0);
    }
    __syncthreads();
#pragma unroll
    for (int kc = 0; kc < 2; ++kc) {
      bf16x8 af[4], bfv[4];
#pragma unroll
      for (int mi = 0; mi < 4; ++mi) {
        int m = wr * 64 + mi * 16 + c;
        af[mi] = *(const bf16x8*)&As[(m * 8 + ((kc * 4 + g) ^ (m & 7))) * 8];
      }
#pragma unroll
      for (int ni = 0; ni < 4; ++ni) {
        int n = wc * 64 + ni * 16 + c;
        bfv[ni] = *(const bf16x8*)&Bs[(n * 8 + ((kc * 4 + g) ^ (n & 7))) * 8];
      }
#pragma unroll
      for (int mi = 0; mi < 4; ++mi)
#pragma unroll
        for (int ni = 0; ni < 4; ++ni)
          acc[mi][ni] = __builtin_amdgcn_mfma_f32_16x16x32_bf16(af[mi], bfv[ni], acc[mi][ni], 0, 0, 0);
    }
  }

#pragma unroll
  for (int ni = 0; ni < 4; ++ni) {
    int col = n0 + wc * 64 + ni * 16 + c;
    float bv = bias[col];
#pragma unroll
    for (int mi = 0; mi < 4; ++mi)
#pragma unroll
      for (int rr = 0; rr < 4; ++rr) {
        int row = m0 + wr * 64 + mi * 16 + g * 4 + rr;
        float v = acc[mi][ni][rr] + bv;
        if (OF32)
          ((float*)Cout)[(size_t)row * Nn + col] = v;
        else
          ((unsigned short*)Cout)[(size_t)row * Nn + col] = f2bf(v);
      }
  }
}

// ---------------- attention: one workgroup per (p, h) ----------------------
// qkv (bf16) is the permuted (N, 1536) buffer; q at col h*64, k at 512+h*64,
// v at 1024+h*64. Output scattered to row order[n] (bf16) so the proj GEMM
// reads contiguously.
// LDS = Ks 32K + Vt 32K + Pt 16K = 80 KB -> 2 blocks/CU (8 waves).
// Pt is per-wave, chunked (16x64) and double-buffered: wave-internal LDS
// ordering via lgkmcnt, NO barriers needed in the t-loop.
__global__ __launch_bounds__(256, 2) void attn_k(const unsigned short* __restrict__ qkv,
                                                 const int* __restrict__ order,
                                                 unsigned short* __restrict__ attnout) {
  __shared__ __align__(16) unsigned short Ks[KTOK * 64];       // [m][d], XOR-swizzled 16B groups
  __shared__ __align__(16) unsigned short Vt[64 * 256];        // [d][m] transposed, XOR-swizzled
  __shared__ __align__(16) unsigned short Pt[4][2][16 * 64];   // per-wave, double-buffered chunk

  int p = blockIdx.x >> 3, h = blockIdx.x & 7;
  int tid = threadIdx.x;
  int wv = tid >> 6, ln = tid & 63, g = ln >> 4, c = ln & 15;

  const unsigned short* base = qkv + (size_t)p * KTOK * C3 + h * DHEAD;

  // stage K rows and V transposed
  {
    const unsigned short* krow = base + CDIM + (size_t)tid * C3;
#pragma unroll
    for (int j = 0; j < 8; ++j) {
      bf16x8 kv = *(const bf16x8*)(krow + j * 8);
      *(bf16x8*)&Ks[(tid * 8 + (j ^ (tid & 7))) * 8] = kv;
    }
    const unsigned short* vrow = base + 2 * CDIM + (size_t)tid * C3;
#pragma unroll
    for (int j = 0; j < 8; ++j) {
      bf16x8 vvv = *(const bf16x8*)(vrow + j * 8);
#pragma unroll
      for (int e = 0; e < 8; ++e) {
        int d = j * 8 + e;
        Vt[d * 256 + (((tid >> 3) ^ (d & 7)) << 3) + (tid & 7)] = (unsigned short)vvv[e];
      }
    }
  }
  __syncthreads();

#pragma unroll 1
  for (int t = 0; t < 4; ++t) {
    int q0 = wv * 64 + t * 16;
    const unsigned short* qrow = base + (size_t)(q0 + c) * C3;
    bf16x8 aq0 = *(const bf16x8*)(qrow + g * 8);
    bf16x8 aq1 = *(const bf16x8*)(qrow + 32 + g * 8);

    // S = Q K^T  (16 q-rows x 256 m-cols), C/D: row=g*4+reg (q), col=c
    f32x4 s[16];
#pragma unroll
    for (int mt = 0; mt < 16; ++mt) {
      int m = mt * 16 + c;
      bf16x8 bk0 = *(const bf16x8*)&Ks[(m * 8 + ((0 + g) ^ (m & 7))) * 8];
      bf16x8 bk1 = *(const bf16x8*)&Ks[(m * 8 + ((4 + g) ^ (m & 7))) * 8];
      f32x4 z = (f32x4){0.f, 0.f, 0.f, 0.f};
      z = __builtin_amdgcn_mfma_f32_16x16x32_bf16(aq0, bk0, z, 0, 0, 0);
      s[mt] = __builtin_amdgcn_mfma_f32_16x16x32_bf16(aq1, bk1, z, 0, 0, 0);
    }

    // softmax over m: 16 mt tiles in-reg + 16 lanes (shfl_xor 1..8, same g)
    float mx[4], sm[4];
#pragma unroll
    for (int rr = 0; rr < 4; ++rr) {
      float m1 = s[0][rr];
#pragma unroll
      for (int mt = 1; mt < 16; ++mt) m1 = fmaxf(m1, s[mt][rr]);
#pragma unroll
      for (int off = 1; off < 16; off <<= 1) m1 = fmaxf(m1, __shfl_xor(m1, off, 64));
      mx[rr] = m1;
    }
#pragma unroll
    for (int rr = 0; rr < 4; ++rr) sm[rr] = 0.f;
#pragma unroll
    for (int mt = 0; mt < 16; ++mt)
#pragma unroll
      for (int rr = 0; rr < 4; ++rr) {
        float e = __expf((s[mt][rr] - mx[rr]) * 0.125f);
        s[mt][rr] = e;
        sm[rr] += e;
      }
#pragma unroll
    for (int rr = 0; rr < 4; ++rr) {
      float t2 = sm[rr];
#pragma unroll
      for (int off = 1; off < 16; off <<= 1) t2 += __shfl_xor(t2, off, 64);
      sm[rr] = 1.f / t2;
    }

    // O = P V, chunked: write 16x64 P-chunk (A-layout) to per-wave LDS,
    // read its two A-frags, MFMA; double-buffer chunk parity for WAR.
    f32x4 o[4];
#pragma unroll
    for (int dt = 0; dt < 4; ++dt) o[dt] = (f32x4){0.f, 0.f, 0.f, 0.f};
#pragma unroll
    for (int ch = 0; ch < 4; ++ch) {
      unsigned short* pt = &Pt[wv][ch & 1][0];
#pragma unroll
      for (int mtl = 0; mtl < 4; ++mtl) {
        int mt = ch * 4 + mtl;
        int mcol = mtl * 16 + c;   // 0..63 within chunk
#pragma unroll
        for (int rr = 0; rr < 4; ++rr) {
          int q = g * 4 + rr;
          pt[q * 64 + (((mcol >> 3) ^ (q & 7)) << 3) + (mcol & 7)] =
              f2bf(s[mt][rr] * sm[rr]);
        }
      }
#pragma unroll
      for (int mcl = 0; mcl < 2; ++mcl) {
        int cg = mcl * 4 + g;              // 8-col group within chunk
        bf16x8 ap = *(const bf16x8*)&pt[(c * 8 + (cg ^ (c & 7))) * 8];
        int cgm = (ch * 2 + mcl) * 4 + g;  // global 8-col group within 256
#pragma unroll
        for (int dt = 0; dt < 4; ++dt) {
          int d = dt * 16 + c;
          bf16x8 bv = *(const bf16x8*)&Vt[(d * 32 + (cgm ^ (d & 7))) * 8];
          o[dt] = __builtin_amdgcn_mfma_f32_16x16x32_bf16(ap, bv, o[dt], 0, 0, 0);
        }
      }
    }

    // scatter-store: row order[p*256 + q], col h*64 + d
#pragma unroll
    for (int rr = 0; rr < 4; ++rr) {
      int orow = order[p * KTOK + q0 + g * 4 + rr];
      size_t rb = (size_t)orow * CDIM + h * DHEAD;
#pragma unroll
      for (int dt = 0; dt < 4; ++dt)
        attnout[rb + dt * 16 + c] = f2bf(o[dt][rr]);
    }
  }
}

extern "C" void kernel_launch(void* const* d_in, const int* in_sizes, int n_in,
                              void* d_out, int out_size, void* d_ws, size_t ws_size,
                              hipStream_t stream) {
  const float* feat  = (const float*)d_in[0];
  const int*   order = (const int*)d_in[1];
  // d_in[2] = inverse (unused: we scatter by order instead)
  const float* Wqkv  = (const float*)d_in[3];
  const float* bqkv  = (const float*)d_in[4];
  const float* Wproj = (const float*)d_in[5];
  const float* bproj = (const float*)d_in[6];
  float* out = (float*)d_out;

  // ws layout (bf16 intermediates):
  //   qkv    : N*1536            = 201.3 MB
  //   featb  : N*512             =  67.1 MB  (dead after gemm1; aliased by attn)
  //   wqkvT  : 1536*512          =   1.6 MB
  //   wprojT : 512*512           =   0.5 MB
  char* ws = (char*)d_ws;
  unsigned short* qkv    = (unsigned short*)ws;
  unsigned short* featb  = (unsigned short*)(ws + (size_t)N_TOK * C3 * 2);
  unsigned short* attn   = featb;  // disjoint lifetime
  unsigned short* wqkvT  = (unsigned short*)(ws + (size_t)N_TOK * C3 * 2 + (size_t)N_TOK * CDIM * 2);
  unsigned short* wprojT = wqkvT + C3 * CDIM;

  // f32 -> bf16 conversions
  cvt_f32_bf16<<<(N_TOK * CDIM) / (256 * 4), 256, 0, stream>>>(feat, featb);
  transpose_cvt<<<dim3(C3 / 32, CDIM / 32), 256, 0, stream>>>(Wqkv, wqkvT, CDIM, C3);
  transpose_cvt<<<dim3(CDIM / 32, CDIM / 32), 256, 0, stream>>>(Wproj, wprojT, CDIM, CDIM);

  // qkv[n,:] = feat[order[n],:] @ Wqkv + bqkv   (permuted rows directly)
  gemm_bt<0><<<(N_TOK / 128) * (C3 / 128), 256, 0, stream>>>(
      featb, wqkvT, bqkv, qkv, order, C3, CDIM, C3 / 128);

  // block-local attention, scatter back to original row order
  attn_k<<<PGRP * HEADS, 256, 0, stream>>>(qkv, order, attn);

  // out = attn @ Wproj + bproj  (f32 output)
  gemm_bt<1><<<(N_TOK / 128) * (CDIM / 128), 256, 0, stream>>>(
      attn, wprojT, bproj, out, nullptr, CDIM, CDIM, CDIM / 128);
}